// Round 5
// baseline (324.582 us; speedup 1.0000x reference)
//
#include <hip/hip_runtime.h>
#include <math.h>

// Problem constants
#define BN   32768
#define DIM  256
#define KC   1024
#define BN_EPS 1e-5f

// Output layout (floats) in d_out
#define QX_SIZE   (BN * DIM)
#define LOSS0_OFF (QX_SIZE)
#define LOSS1_OFF (QX_SIZE + 1)
#define IDX_OFF   (QX_SIZE + 2)
#define PERP_OFF  (QX_SIZE + 2 + BN)

// Workspace (float offsets)
#define WS_SUM    0     // 256
#define WS_SUMSQ  256   // 256
#define WS_COUNT  512   // 1
#define WS_LOSS   513   // 1
#define WS_COUNTS 1024  // 1024
#define WS_CNORM  3072  // 1024
#define WS_EBH    8192                  // bf16-hi frags, 131072 floats
#define WS_EBL    (8192 + 131072)       // bf16-lo frags, 131072 floats
#define WS_ETP    (8192 + 262144)       // eT [K][D] f32 when packed layout
#define WS_ET_LEG 8192                  // eT offset in legacy (small-ws) layout

typedef short bf16x8  __attribute__((ext_vector_type(8)));
typedef float f32x4   __attribute__((ext_vector_type(4)));
typedef float fvec4   __attribute__((ext_vector_type(4)));
typedef int   int4v   __attribute__((ext_vector_type(4)));

static __device__ inline unsigned short f2bf(float f) {
    unsigned int u = __float_as_uint(f);
    return (unsigned short)((u + 0x7FFFu + ((u >> 16) & 1u)) >> 16);
}
static __device__ inline fvec4 nt_ld4(const void* p) {
    return __builtin_nontemporal_load((const fvec4*)p);
}
static __device__ inline void nt_st(float* p, float v) {
    __builtin_nontemporal_store(v, p);
}

// ---------------------------------------------------------------- kernel 1
// Blocks 0..255: masked stats (128 rows each). 256..259: cnorm.
// 260..323: e -> eT transpose into ws + (use_pk) B-fragment bf16 pack.
__global__ __launch_bounds__(256) void k_pre(const float* __restrict__ x,
                                             const int* __restrict__ mask,
                                             const float* __restrict__ e,
                                             float* __restrict__ ws,
                                             int use_et, int use_pk, int et_off) {
    int t = threadIdx.x;
    int b = blockIdx.x;
    if (b >= 260) {                        // transpose tiles 64d x 64k
        if (!use_et) return;
        int b2 = b - 260;
        int d0 = (b2 >> 4) * 64;           // contraction (feature) rows
        int k0 = (b2 & 15) * 64;           // codes
        __shared__ float tile[64][65];
        int c = t & 63;
        int rq = t >> 6;
        #pragma unroll
        for (int p = 0; p < 16; ++p) {
            int dd = p * 4 + rq;
            tile[dd][c] = e[(size_t)(d0 + dd) * KC + k0 + c];
        }
        __syncthreads();
        #pragma unroll
        for (int p = 0; p < 16; ++p) {
            int kk = p * 4 + rq;
            nt_st(&ws[et_off + (size_t)(k0 + kk) * DIM + d0 + c], tile[c][kk]);
        }
        if (use_pk) {
            // pack 8 fragments (4 code-tiles x 2 k-chunks) from the tile.
            // Bit-identical to the in-loop truncate split of earlier rounds.
            short* pbh = (short*)(ws + WS_EBH);
            short* pbl = (short*)(ws + WS_EBL);
            int lane2 = t & 63;
            int g = t >> 6;                 // 0..3
            int quad2 = lane2 >> 4, col2 = lane2 & 15;
            #pragma unroll
            for (int f = 0; f < 2; ++f) {
                int fi = g * 2 + f;         // 0..7
                int ctl = fi >> 1, kcl = fi & 1;
                int ct = (b2 & 15) * 4 + ctl;       // code-tile 0..63
                int kc = (b2 >> 4) * 2 + kcl;       // k-chunk 0..7
                bf16x8 hv, lv;
                #pragma unroll
                for (int j = 0; j < 8; ++j) {
                    float v = tile[kcl * 32 + quad2 * 8 + j][ctl * 16 + col2];
                    unsigned u = __float_as_uint(v);
                    hv[j] = (short)(u >> 16);
                    float lf = v - __uint_as_float(u & 0xffff0000u);
                    lv[j] = (short)(__float_as_uint(lf) >> 16);
                }
                size_t fb = ((size_t)(ct * 8 + kc) * 64 + lane2) * 8;
                *(bf16x8*)(pbh + fb) = hv;
                *(bf16x8*)(pbl + fb) = lv;
            }
        }
        return;
    }
    if (b >= 256) {                        // cnorm
        int k = (b - 256) * 256 + t;
        float acc = 0.f;
        #pragma unroll 8
        for (int d = 0; d < DIM; ++d) {
            float v = e[(size_t)d * KC + k];
            acc = fmaf(v, v, acc);
        }
        ws[WS_CNORM + k] = acc;
        return;
    }
    __shared__ float s4[4 * 256];
    __shared__ float q4[4 * 256];
    __shared__ float cntS[4];
    int c4 = t & 63;
    int rsub = t >> 6;
    float s0=0.f,s1=0.f,s2=0.f,s3=0.f, q0=0.f,q1=0.f,q2=0.f,q3=0.f, cnt=0.f;
    int rbase = b * 4 + rsub;
    for (int i = 0; i < 32; ++i) {
        int r = rbase + i * 1024;
        float m = (float)mask[r];
        fvec4 v = nt_ld4(&x[(size_t)r * DIM + c4 * 4]);
        cnt += m;
        float m0 = m*v.x, m1 = m*v.y, m2 = m*v.z, m3 = m*v.w;
        s0 += m0; s1 += m1; s2 += m2; s3 += m3;
        q0 = fmaf(m0, v.x, q0); q1 = fmaf(m1, v.y, q1);
        q2 = fmaf(m2, v.z, q2); q3 = fmaf(m3, v.w, q3);
    }
    int f = c4 * 4;
    s4[rsub * 256 + f + 0] = s0; s4[rsub * 256 + f + 1] = s1;
    s4[rsub * 256 + f + 2] = s2; s4[rsub * 256 + f + 3] = s3;
    q4[rsub * 256 + f + 0] = q0; q4[rsub * 256 + f + 1] = q1;
    q4[rsub * 256 + f + 2] = q2; q4[rsub * 256 + f + 3] = q3;
    if (c4 == 0) cntS[rsub] = cnt;
    __syncthreads();
    float stot = s4[t] + s4[256 + t] + s4[512 + t] + s4[768 + t];
    float qtot = q4[t] + q4[256 + t] + q4[512 + t] + q4[768 + t];
    atomicAdd(&ws[WS_SUM + t], stot);
    atomicAdd(&ws[WS_SUMSQ + t], qtot);
    if (t == 0)
        atomicAdd(&ws[WS_COUNT], cntS[0] + cntS[1] + cntS[2] + cntS[3]);
}

// ---------------------------------------------------------------- kernel 3
// MFMA main, counted-vmcnt pipeline (T3+T4 template). 256 threads (4 waves),
// 64 rows/block (wave w owns rows w*16..w*16+15, A-fragments in registers),
// grid 512. All waves share B chunks staged cooperatively via
// global_load_lds into a 4-buffer LDS ring, depth-2 prefetch:
//   stage(ci+2); s_waitcnt vmcnt(4); s_barrier; ds_read+MFMA
// Loads stay in flight ACROSS barriers — never vmcnt(0) in steady state.
#define NCHUNK 128   // 16 code-groups x 8 k-chunks
#define CHUNKB 8192  // 8 frags x 1KB

#define CHUNK_COMPUTE(kcc)                                                   \
    {                                                                        \
        const char* bufb = (const char*)&Bs[((kcc) & 3) * CHUNKB];           \
        __builtin_amdgcn_s_setprio(1);                                       \
        _Pragma("unroll")                                                    \
        for (int nt = 0; nt < 4; ++nt) {                                     \
            bf16x8 bh = *(const bf16x8*)(bufb + (nt * 2 + 0) * 1024 + lane * 16); \
            bf16x8 bl = *(const bf16x8*)(bufb + (nt * 2 + 1) * 1024 + lane * 16); \
            acc[nt] = __builtin_amdgcn_mfma_f32_16x16x32_bf16(ah[kcc], bh, acc[nt], 0, 0, 0); \
            acc[nt] = __builtin_amdgcn_mfma_f32_16x16x32_bf16(ah[kcc], bl, acc[nt], 0, 0, 0); \
            acc[nt] = __builtin_amdgcn_mfma_f32_16x16x32_bf16(al[kcc], bh, acc[nt], 0, 0, 0); \
        }                                                                    \
        __builtin_amdgcn_s_setprio(0);                                       \
    }

#define SCORE_MERGE(gg)                                                      \
    {                                                                        \
        _Pragma("unroll")                                                    \
        for (int r = 0; r < 4; ++r) {                                        \
            float v = 3.4e38f; int ii = 0;                                   \
            _Pragma("unroll")                                                \
            for (int nt = 0; nt < 4; ++nt) {                                 \
                int kcode = (gg) * 64 + nt * 16 + col0;                      \
                float s = fmaf(-2.f, acc[nt][r], cnS[kcode]);                \
                if (s < v) { v = s; ii = kcode; }                            \
            }                                                                \
            _Pragma("unroll")                                                \
            for (int m2 = 1; m2 < 16; m2 <<= 1) {                            \
                float v2 = __shfl_xor(v, m2, 64);                            \
                int   i2 = __shfl_xor(ii, m2, 64);                           \
                if (v2 < v || (v2 == v && i2 < ii)) { v = v2; ii = i2; }     \
            }                                                                \
            if (v < bv[r] || (v == bv[r] && ii < bi_[r])) {                  \
                bv[r] = v; bi_[r] = ii;                                      \
            }                                                                \
        }                                                                    \
        _Pragma("unroll")                                                    \
        for (int nt = 0; nt < 4; ++nt)                                       \
            acc[nt] = (f32x4){0.f, 0.f, 0.f, 0.f};                           \
    }

__global__ __launch_bounds__(256, 3) void k_main_mfma(
        const float* __restrict__ x, const int* __restrict__ mask,
        const float* __restrict__ e, const float* __restrict__ gamma,
        const float* __restrict__ beta,
        const float* __restrict__ ws, float* __restrict__ out, int use_pk) {
    __shared__ __align__(16) char Bs[4 * CHUNKB];   // 32 KB B ring
    __shared__ float muS[DIM], scS[DIM], btS[DIM];
    __shared__ float cnS[KC];

    const int tid = threadIdx.x;
    const int row0 = blockIdx.x * 64;
    const int w = tid >> 6;          // 0..3
    const int lane = tid & 63;
    const int quad = lane >> 4;
    const int col0 = lane & 15;

    {
        float cnt = ws[WS_COUNT];
        float nv = fmaxf(cnt, 1.f);
        float mu = ws[WS_SUM + tid] / nv;
        float var = ws[WS_SUMSQ + tid] / nv - mu * mu;
        var = fmaxf(var, 0.f);
        muS[tid] = mu;
        scS[tid] = rsqrtf(var + BN_EPS) * gamma[tid];
        btS[tid] = beta[tid];
    }
    #pragma unroll
    for (int p = 0; p < 4; ++p)
        cnS[p * 256 + tid] = ws[WS_CNORM + p * 256 + tid];
    __syncthreads();

    // ---- A fragments in registers: wave w rows w*16+col0, k = kc*32+quad*8+j
    bf16x8 ah[8], al[8];
    {
        const float* xr = x + (size_t)(row0 + w * 16 + col0) * DIM;
        #pragma unroll
        for (int kc = 0; kc < 8; ++kc) {
            int k0 = kc * 32 + quad * 8;
            fvec4 v0 = nt_ld4(xr + k0);
            fvec4 v1 = nt_ld4(xr + k0 + 4);
            float xv[8] = {v0.x, v0.y, v0.z, v0.w, v1.x, v1.y, v1.z, v1.w};
            bf16x8 hv, lv;
            #pragma unroll
            for (int j = 0; j < 8; ++j) {
                float xb = fmaf(xv[j] - muS[k0 + j], scS[k0 + j], btS[k0 + j]);
                unsigned short h = f2bf(xb);
                float hf = __uint_as_float((unsigned)h << 16);
                hv[j] = (short)h;
                lv[j] = (short)f2bf(xb - hf);
            }
            ah[kc] = hv;
            al[kc] = lv;
        }
    }
    // retire A loads so the counted-vmcnt math below sees only stage loads
    asm volatile("s_waitcnt vmcnt(0)" ::: "memory");
    __builtin_amdgcn_sched_barrier(0);

    f32x4 acc[4];
    #pragma unroll
    for (int nt = 0; nt < 4; ++nt)
        acc[nt] = (f32x4){0.f, 0.f, 0.f, 0.f};
    float bv[4] = {3.4e38f, 3.4e38f, 3.4e38f, 3.4e38f};
    int   bi_[4] = {0, 0, 0, 0};

    if (use_pk) {
        const char* pbh8 = (const char*)(ws + WS_EBH);
        const char* pbl8 = (const char*)(ws + WS_EBL);
        // wave w stages frag nt=w (hi+lo) of each chunk; LDS dst wave-uniform,
        // global src per-lane 16B contiguous (1KB/instruction).
        auto stage = [&](int gg, int kcc, int bufi) {
            const int ct = gg * 4 + w;
            const size_t foff = (size_t)(((ct * 8 + kcc) * 64 + lane) * 16);
            char* d0 = &Bs[bufi * CHUNKB + (w * 2 + 0) * 1024];
            char* d1 = &Bs[bufi * CHUNKB + (w * 2 + 1) * 1024];
            __builtin_amdgcn_global_load_lds(
                (const __attribute__((address_space(1))) void*)(pbh8 + foff),
                (__attribute__((address_space(3))) void*)d0, 16, 0, 0);
            __builtin_amdgcn_global_load_lds(
                (const __attribute__((address_space(1))) void*)(pbl8 + foff),
                (__attribute__((address_space(3))) void*)d1, 16, 0, 0);
        };

        stage(0, 0, 0);          // chunk 0
        stage(0, 1, 1);          // chunk 1

        for (int g = 0; g < 15; ++g) {
            #pragma unroll
            for (int kc = 0; kc < 8; ++kc) {
                int ci2 = g * 8 + kc + 2;
                stage(ci2 >> 3, ci2 & 7, (kc + 2) & 3);
                asm volatile("s_waitcnt vmcnt(4)" ::: "memory");
                __builtin_amdgcn_s_barrier();
                CHUNK_COMPUTE(kc);
            }
            SCORE_MERGE(g);
        }
        // peeled last group with counted drain (never blanket vmcnt(0) early)
        {
            #pragma unroll
            for (int kc = 0; kc < 8; ++kc) {
                if (kc < 6) {
                    stage(15, (kc + 2) & 7, (kc + 2) & 3);
                    asm volatile("s_waitcnt vmcnt(4)" ::: "memory");
                } else if (kc == 6) {
                    asm volatile("s_waitcnt vmcnt(2)" ::: "memory");
                } else {
                    asm volatile("s_waitcnt vmcnt(0)" ::: "memory");
                }
                __builtin_amdgcn_s_barrier();
                CHUNK_COMPUTE(kc);
            }
            SCORE_MERGE(15);
        }
    } else {
        // fallback: direct scattered loads from e (d_in, L2-cached), in-reg split
        for (int g = 0; g < 16; ++g) {
            #pragma unroll
            for (int kc = 0; kc < 8; ++kc) {
                const float* ep = e + (size_t)(kc * 32 + quad * 8) * KC
                                    + g * 64 + col0;
                #pragma unroll
                for (int nt = 0; nt < 4; ++nt) {
                    const float* epn = ep + nt * 16;
                    float bvv[8];
                    #pragma unroll
                    for (int j = 0; j < 8; ++j)
                        bvv[j] = epn[(size_t)j * KC];
                    int4v hw, lw;
                    #pragma unroll
                    for (int p = 0; p < 4; ++p) {
                        unsigned u0 = __float_as_uint(bvv[2 * p]);
                        unsigned u1 = __float_as_uint(bvv[2 * p + 1]);
                        hw[p] = (int)__builtin_amdgcn_perm(u1, u0, 0x07060302u);
                        float l0 = bvv[2 * p]     - __uint_as_float(u0 & 0xffff0000u);
                        float l1 = bvv[2 * p + 1] - __uint_as_float(u1 & 0xffff0000u);
                        lw[p] = (int)__builtin_amdgcn_perm(__float_as_uint(l1),
                                                           __float_as_uint(l0),
                                                           0x07060302u);
                    }
                    bf16x8 bh = __builtin_bit_cast(bf16x8, hw);
                    bf16x8 bl = __builtin_bit_cast(bf16x8, lw);
                    acc[nt] = __builtin_amdgcn_mfma_f32_16x16x32_bf16(ah[kc], bh, acc[nt], 0, 0, 0);
                    acc[nt] = __builtin_amdgcn_mfma_f32_16x16x32_bf16(ah[kc], bl, acc[nt], 0, 0, 0);
                    acc[nt] = __builtin_amdgcn_mfma_f32_16x16x32_bf16(al[kc], bh, acc[nt], 0, 0, 0);
                }
            }
            SCORE_MERGE(g);
        }
    }

    // ---- per-wave result write: lanes col0==0 own 4 rows each
    if (col0 == 0) {
        #pragma unroll
        for (int r = 0; r < 4; ++r) {
            int rl = w * 16 + quad * 4 + r;
            int m = mask[row0 + rl];
            out[IDX_OFF + row0 + rl] = m ? (float)bi_[r] : -1.0f;
            if (m) atomicAdd((float*)&ws[WS_COUNTS + bi_[r]], 1.0f);
        }
    }
}

// ---------------------------------------------------------------- kernel 3b
// Streaming epilogue: recompute xb (fp32) from x, gather q from eT rows
// (coalesced), write quantized output + accumulate loss.
__global__ __launch_bounds__(256) void k_epi(
        const float* __restrict__ x, const int* __restrict__ mask,
        const float* __restrict__ e, const float* __restrict__ gamma,
        const float* __restrict__ beta,
        const float* __restrict__ ws, float* __restrict__ out,
        int use_et, int et_off) {
    __shared__ __align__(16) float muS[DIM], scS[DIM], btS[DIM];
    __shared__ float wred[4];
    const int tid = threadIdx.x;
    const int row0 = blockIdx.x * 32;
    const int w = tid >> 6;
    const int lane = tid & 63;
    {
        float cnt = ws[WS_COUNT];
        float nv = fmaxf(cnt, 1.f);
        float mu = ws[WS_SUM + tid] / nv;
        float var = ws[WS_SUMSQ + tid] / nv - mu * mu;
        var = fmaxf(var, 0.f);
        muS[tid] = mu;
        scS[tid] = rsqrtf(var + BN_EPS) * gamma[tid];
        btS[tid] = beta[tid];
    }
    __syncthreads();

    const int d0 = lane * 4;
    fvec4 mu4 = *(const fvec4*)&muS[d0];
    fvec4 sc4 = *(const fvec4*)&scS[d0];
    fvec4 bt4 = *(const fvec4*)&btS[d0];
    const float* et = ws + et_off;
    float lacc = 0.f;
    #pragma unroll
    for (int rr = 0; rr < 8; ++rr) {
        const int row = row0 + w * 8 + rr;
        const int m = mask[row];
        const float fm = (float)m;
        const int idx = m ? (int)out[IDX_OFF + row] : 0;
        fvec4 xv = nt_ld4(&x[(size_t)row * DIM + d0]);
        fvec4 g;
        if (use_et) {
            g = nt_ld4(&et[(size_t)idx * DIM + d0]);
        } else {
            g.x = e[(size_t)(d0 + 0) * KC + idx];
            g.y = e[(size_t)(d0 + 1) * KC + idx];
            g.z = e[(size_t)(d0 + 2) * KC + idx];
            g.w = e[(size_t)(d0 + 3) * KC + idx];
        }
        fvec4 q;
        float dsum = 0.f;
        #pragma unroll
        for (int i = 0; i < 4; ++i) {
            float xb = fmaf(xv[i] - mu4[i], sc4[i], bt4[i]);
            float diff = xb - g[i];
            dsum = fmaf(diff, diff, dsum);
            q[i] = fm * g[i];
        }
        lacc = fmaf(fm, dsum, lacc);
        __builtin_nontemporal_store(q, (fvec4*)&out[(size_t)row * DIM + d0]);
    }
    #pragma unroll
    for (int off2 = 32; off2 > 0; off2 >>= 1)
        lacc += __shfl_down(lacc, off2, 64);
    if (lane == 0) wred[w] = lacc;
    __syncthreads();
    if (tid == 0)
        atomicAdd((float*)&ws[WS_LOSS], wred[0] + wred[1] + wred[2] + wred[3]);
}

// ---------------------------------------------------------------- kernel 4
__global__ __launch_bounds__(256) void k_final(const float* __restrict__ ws,
                                               float* __restrict__ out) {
    int t = threadIdx.x;
    __shared__ float wr[4];
    float nv = fmaxf(ws[WS_COUNT], 1.f);
    float acc = 0.f;
    for (int j = t; j < KC; j += 256) {
        float p = ws[WS_COUNTS + j] / nv;
        acc = fmaf(p, logf(p + 1e-10f), acc);
    }
    #pragma unroll
    for (int off = 32; off > 0; off >>= 1) acc += __shfl_down(acc, off, 64);
    if ((t & 63) == 0) wr[t >> 6] = acc;
    __syncthreads();
    if (t == 0) {
        float ent = wr[0] + wr[1] + wr[2] + wr[3];
        float loss = ws[WS_LOSS] / (nv * (float)DIM);
        out[LOSS0_OFF] = loss;
        out[LOSS1_OFF] = loss;
        out[PERP_OFF] = expf(-ent);
    }
}

// ---------------------------------------------------------------- launch
extern "C" void kernel_launch(void* const* d_in, const int* in_sizes, int n_in,
                              void* d_out, int out_size, void* d_ws, size_t ws_size,
                              hipStream_t stream) {
    const float* x     = (const float*)d_in[0];
    const int*   amask = (const int*)d_in[1];
    const float* e     = (const float*)d_in[2];
    const float* gamma = (const float*)d_in[3];
    const float* beta  = (const float*)d_in[4];
    float* out = (float*)d_out;
    float* ws  = (float*)d_ws;

    size_t need_pk = (size_t)(WS_ETP + KC * DIM) * sizeof(float);    // ~2.03 MB
    size_t need_et = (size_t)(WS_ET_LEG + KC * DIM) * sizeof(float); // ~1.03 MB
    int use_pk = ws_size >= need_pk;
    int use_et = use_pk ? 1 : (ws_size >= need_et ? 1 : 0);
    int et_off = use_pk ? WS_ETP : WS_ET_LEG;

    (void)hipMemsetAsync(d_ws, 0, 8192, stream);

    k_pre<<<324, 256, 0, stream>>>(x, amask, e, ws, use_et, use_pk, et_off);
    k_main_mfma<<<BN / 64, 256, 0, stream>>>(x, amask, e, gamma, beta, ws, out,
                                             use_pk);
    k_epi<<<BN / 32, 256, 0, stream>>>(x, amask, e, gamma, beta, ws, out,
                                       use_et, et_off);
    k_final<<<1, 256, 0, stream>>>(ws, out);
}

// Round 6
// 313.720 us; speedup vs baseline: 1.0346x; 1.0346x over previous
//
#include <hip/hip_runtime.h>
#include <math.h>

// Problem constants
#define BN   32768
#define DIM  256
#define KC   1024
#define BN_EPS 1e-5f

// Output layout (floats) in d_out
#define QX_SIZE   (BN * DIM)
#define LOSS0_OFF (QX_SIZE)
#define LOSS1_OFF (QX_SIZE + 1)
#define IDX_OFF   (QX_SIZE + 2)
#define PERP_OFF  (QX_SIZE + 2 + BN)

// Scratch partials parked in the (later overwritten) QX region of out:
#define PART_V 0           // [2][BN] slice-min values
#define PART_I (2 * BN)    // [2][BN] slice-argmin indices (as float)

// Workspace (float offsets)
#define WS_SUM    0     // 256
#define WS_SUMSQ  256   // 256
#define WS_COUNT  512   // 1
#define WS_LOSS   513   // 1
#define WS_COUNTS 1024  // 1024
#define WS_CNORM  3072  // 1024
#define WS_PK     8192                  // packed B chunks, 262144 floats (1MB)
#define WS_ETX    (8192 + 262144)       // eT [K][D] f32 (packed layout)
#define WS_ET_LEG 8192                  // eT offset in legacy (small-ws) layout

typedef short bf16x8  __attribute__((ext_vector_type(8)));
typedef float f32x4   __attribute__((ext_vector_type(4)));
typedef float fvec4   __attribute__((ext_vector_type(4)));
typedef int   int4v   __attribute__((ext_vector_type(4)));

static __device__ inline unsigned short f2bf(float f) {
    unsigned int u = __float_as_uint(f);
    return (unsigned short)((u + 0x7FFFu + ((u >> 16) & 1u)) >> 16);
}
static __device__ inline fvec4 nt_ld4(const void* p) {
    return __builtin_nontemporal_load((const fvec4*)p);
}
static __device__ inline void nt_st(float* p, float v) {
    __builtin_nontemporal_store(v, p);
}

// ---------------------------------------------------------------- kernel 1
// Blocks 0..255: masked stats. 256..259: cnorm. 260..323: transpose + pack.
__global__ __launch_bounds__(256) void k_pre(const float* __restrict__ x,
                                             const int* __restrict__ mask,
                                             const float* __restrict__ e,
                                             float* __restrict__ ws,
                                             int use_et, int use_pk, int et_off) {
    int t = threadIdx.x;
    int b = blockIdx.x;
    if (b >= 260) {                        // transpose tiles 64d x 64k
        if (!use_et) return;
        int b2 = b - 260;
        int d0 = (b2 >> 4) * 64;           // contraction (feature) rows
        int k0 = (b2 & 15) * 64;           // codes
        __shared__ float tile[64][65];
        int c = t & 63;
        int rq = t >> 6;
        #pragma unroll
        for (int p = 0; p < 16; ++p) {
            int dd = p * 4 + rq;
            tile[dd][c] = e[(size_t)(d0 + dd) * KC + k0 + c];
        }
        __syncthreads();
        #pragma unroll
        for (int p = 0; p < 16; ++p) {
            int kk = p * 4 + rq;
            nt_st(&ws[et_off + (size_t)(k0 + kk) * DIM + d0 + c], tile[c][kk]);
        }
        if (use_pk) {
            // Pack chunk-ordered B: chunk (G=code-group,kcg=k-chunk) is 8KB:
            // frag (nt,h) 1KB, lane (quad=k-sub, col0=code) 16B.
            // Truncate split bit-identical to earlier rounds.
            char* pk = (char*)(ws + WS_PK);
            int lane2 = t & 63;
            int fgrp = t >> 6;              // 0..3
            int quad2 = lane2 >> 4, col2 = lane2 & 15;
            int G = b2 & 15;
            #pragma unroll
            for (int p = 0; p < 4; ++p) {
                int fi = fgrp * 4 + p;      // 0..15
                int kcl = fi >> 3;          // 0..1
                int nt = (fi >> 1) & 3;
                int h = fi & 1;
                int kcg = (b2 >> 4) * 2 + kcl;
                bf16x8 ov;
                #pragma unroll
                for (int j = 0; j < 8; ++j) {
                    float v = tile[kcl * 32 + quad2 * 8 + j][nt * 16 + col2];
                    unsigned u = __float_as_uint(v);
                    if (h == 0) {
                        ov[j] = (short)(u >> 16);
                    } else {
                        float lf = v - __uint_as_float(u & 0xffff0000u);
                        ov[j] = (short)(__float_as_uint(lf) >> 16);
                    }
                }
                size_t off = ((size_t)((G * 8 + kcg) * 8 + nt * 2 + h) << 10)
                             + (size_t)lane2 * 16;
                *(bf16x8*)(pk + off) = ov;
            }
        }
        return;
    }
    if (b >= 256) {                        // cnorm
        int k = (b - 256) * 256 + t;
        float acc = 0.f;
        #pragma unroll 8
        for (int d = 0; d < DIM; ++d) {
            float v = e[(size_t)d * KC + k];
            acc = fmaf(v, v, acc);
        }
        ws[WS_CNORM + k] = acc;
        return;
    }
    __shared__ float s4[4 * 256];
    __shared__ float q4[4 * 256];
    __shared__ float cntS[4];
    int c4 = t & 63;
    int rsub = t >> 6;
    float s0=0.f,s1=0.f,s2=0.f,s3=0.f, q0=0.f,q1=0.f,q2=0.f,q3=0.f, cnt=0.f;
    int rbase = b * 4 + rsub;
    for (int i = 0; i < 32; ++i) {
        int r = rbase + i * 1024;
        float m = (float)mask[r];
        fvec4 v = nt_ld4(&x[(size_t)r * DIM + c4 * 4]);
        cnt += m;
        float m0 = m*v.x, m1 = m*v.y, m2 = m*v.z, m3 = m*v.w;
        s0 += m0; s1 += m1; s2 += m2; s3 += m3;
        q0 = fmaf(m0, v.x, q0); q1 = fmaf(m1, v.y, q1);
        q2 = fmaf(m2, v.z, q2); q3 = fmaf(m3, v.w, q3);
    }
    int f = c4 * 4;
    s4[rsub * 256 + f + 0] = s0; s4[rsub * 256 + f + 1] = s1;
    s4[rsub * 256 + f + 2] = s2; s4[rsub * 256 + f + 3] = s3;
    q4[rsub * 256 + f + 0] = q0; q4[rsub * 256 + f + 1] = q1;
    q4[rsub * 256 + f + 2] = q2; q4[rsub * 256 + f + 3] = q3;
    if (c4 == 0) cntS[rsub] = cnt;
    __syncthreads();
    float stot = s4[t] + s4[256 + t] + s4[512 + t] + s4[768 + t];
    float qtot = q4[t] + q4[256 + t] + q4[512 + t] + q4[768 + t];
    atomicAdd(&ws[WS_SUM + t], stot);
    atomicAdd(&ws[WS_SUMSQ + t], qtot);
    if (t == 0)
        atomicAdd(&ws[WS_COUNT], cntS[0] + cntS[1] + cntS[2] + cntS[3]);
}

// ---------------------------------------------------------------- kernel 3
// MFMA main, codebook-sliced. 512 threads (8 waves), 128 rows/block,
// slice = 512 codes (512KB B per block, HALF of all prior rounds).
// Grid 512 = 256 row-blocks x 2 slices. Chunk = 64 codes x 32 k (8KB);
// staged cooperatively: ONE global_load_lds (1KB) per wave per chunk into a
// 4-slot LDS ring, depth-2, vmcnt(2), single s_barrier per chunk.
// Partial (min,idx) per row written to out's QX scratch; k_merge combines.

#define CHUNK_COMPUTE(slot, kcc)                                             \
    {                                                                        \
        const char* bufb = &Bs[(slot) * 8192];                               \
        __builtin_amdgcn_s_setprio(1);                                       \
        _Pragma("unroll")                                                    \
        for (int nt = 0; nt < 4; ++nt) {                                     \
            bf16x8 bh = *(const bf16x8*)(bufb + (nt * 2 + 0) * 1024 + lane * 16); \
            bf16x8 bl = *(const bf16x8*)(bufb + (nt * 2 + 1) * 1024 + lane * 16); \
            acc[nt] = __builtin_amdgcn_mfma_f32_16x16x32_bf16(ah[kcc], bh, acc[nt], 0, 0, 0); \
            acc[nt] = __builtin_amdgcn_mfma_f32_16x16x32_bf16(ah[kcc], bl, acc[nt], 0, 0, 0); \
            acc[nt] = __builtin_amdgcn_mfma_f32_16x16x32_bf16(al[kcc], bh, acc[nt], 0, 0, 0); \
        }                                                                    \
        __builtin_amdgcn_s_setprio(0);                                       \
    }

#define SCORE_MERGE(gg)                                                      \
    {                                                                        \
        _Pragma("unroll")                                                    \
        for (int r = 0; r < 4; ++r) {                                        \
            float v = 3.4e38f; int ii = 0;                                   \
            _Pragma("unroll")                                                \
            for (int nt = 0; nt < 4; ++nt) {                                 \
                int kl = (gg) * 64 + nt * 16 + col0;                         \
                float sc = fmaf(-2.f, acc[nt][r], cnS[kl]);                  \
                if (sc < v) { v = sc; ii = kl; }                             \
            }                                                                \
            _Pragma("unroll")                                                \
            for (int m2 = 1; m2 < 16; m2 <<= 1) {                            \
                float v2 = __shfl_xor(v, m2, 64);                            \
                int   i2 = __shfl_xor(ii, m2, 64);                           \
                if (v2 < v || (v2 == v && i2 < ii)) { v = v2; ii = i2; }     \
            }                                                                \
            if (v < bv[r] || (v == bv[r] && ii < bi_[r])) {                  \
                bv[r] = v; bi_[r] = ii;                                      \
            }                                                                \
        }                                                                    \
        _Pragma("unroll")                                                    \
        for (int nt = 0; nt < 4; ++nt)                                       \
            acc[nt] = (f32x4){0.f, 0.f, 0.f, 0.f};                           \
    }

__global__ __launch_bounds__(512, 4) void k_main_mfma(
        const float* __restrict__ x, const int* __restrict__ mask,
        const float* __restrict__ e, const float* __restrict__ gamma,
        const float* __restrict__ beta,
        const float* __restrict__ ws, float* __restrict__ out, int use_pk) {
    __shared__ __align__(16) char Bs[4 * 8192];   // 32 KB B ring
    __shared__ float muS[DIM], scS[DIM], btS[DIM];
    __shared__ float cnS[512];

    const int tid = threadIdx.x;
    const int rb = blockIdx.x >> 1;
    const int s = blockIdx.x & 1;        // codebook slice
    const int row0 = rb * 128;
    const int w = tid >> 6;              // 0..7
    const int lane = tid & 63;
    const int quad = lane >> 4;
    const int col0 = lane & 15;

    if (tid < 256) {
        float cnt = ws[WS_COUNT];
        float nv = fmaxf(cnt, 1.f);
        float mu = ws[WS_SUM + tid] / nv;
        float var = ws[WS_SUMSQ + tid] / nv - mu * mu;
        var = fmaxf(var, 0.f);
        muS[tid] = mu;
        scS[tid] = rsqrtf(var + BN_EPS) * gamma[tid];
        btS[tid] = beta[tid];
    }
    cnS[tid] = ws[WS_CNORM + s * 512 + tid];
    __syncthreads();

    // ---- A fragments in registers: wave w rows row0+w*16+col0
    bf16x8 ah[8], al[8];
    {
        const float* xr = x + (size_t)(row0 + w * 16 + col0) * DIM;
        #pragma unroll
        for (int kc = 0; kc < 8; ++kc) {
            int k0 = kc * 32 + quad * 8;
            fvec4 v0 = nt_ld4(xr + k0);
            fvec4 v1 = nt_ld4(xr + k0 + 4);
            float xv[8] = {v0.x, v0.y, v0.z, v0.w, v1.x, v1.y, v1.z, v1.w};
            bf16x8 hv, lv;
            #pragma unroll
            for (int j = 0; j < 8; ++j) {
                float xb = fmaf(xv[j] - muS[k0 + j], scS[k0 + j], btS[k0 + j]);
                unsigned short h = f2bf(xb);
                float hf = __uint_as_float((unsigned)h << 16);
                hv[j] = (short)h;
                lv[j] = (short)f2bf(xb - hf);
            }
            ah[kc] = hv;
            al[kc] = lv;
        }
    }
    // retire A loads so the counted-vmcnt math sees only stage loads
    asm volatile("s_waitcnt vmcnt(0)" ::: "memory");
    __builtin_amdgcn_sched_barrier(0);

    f32x4 acc[4];
    #pragma unroll
    for (int nt = 0; nt < 4; ++nt)
        acc[nt] = (f32x4){0.f, 0.f, 0.f, 0.f};
    float bv[4] = {3.4e38f, 3.4e38f, 3.4e38f, 3.4e38f};
    int   bi_[4] = {0, 0, 0, 0};

    if (use_pk) {
        const char* pkb = (const char*)(ws + WS_PK) + (size_t)s * 524288;
        auto stage = [&](int c2, int slot) {
            const char* src = pkb + (size_t)c2 * 8192 + w * 1024 + lane * 16;
            char* dst = &Bs[slot * 8192 + w * 1024];
            __builtin_amdgcn_global_load_lds(
                (const __attribute__((address_space(1))) void*)src,
                (__attribute__((address_space(3))) void*)dst, 16, 0, 0);
        };
        stage(0, 0);
        stage(1, 1);
        for (int g = 0; g < 7; ++g) {
            #pragma unroll
            for (int kc = 0; kc < 8; ++kc) {
                stage(g * 8 + kc + 2, (kc + 2) & 3);
                asm volatile("s_waitcnt vmcnt(2)" ::: "memory");
                __builtin_amdgcn_s_barrier();
                __builtin_amdgcn_sched_barrier(0);
                CHUNK_COMPUTE(kc & 3, kc);
            }
            SCORE_MERGE(g);
        }
        {   // g = 7, counted drain
            #pragma unroll
            for (int kc = 0; kc < 8; ++kc) {
                if (kc < 6) {
                    stage(56 + kc + 2, (kc + 2) & 3);
                    asm volatile("s_waitcnt vmcnt(2)" ::: "memory");
                } else if (kc == 6) {
                    asm volatile("s_waitcnt vmcnt(1)" ::: "memory");
                } else {
                    asm volatile("s_waitcnt vmcnt(0)" ::: "memory");
                }
                __builtin_amdgcn_s_barrier();
                __builtin_amdgcn_sched_barrier(0);
                CHUNK_COMPUTE(kc & 3, kc);
            }
            SCORE_MERGE(7);
        }
    } else {
        // fallback: scattered loads from e (slice-local), in-reg split
        for (int g = 0; g < 8; ++g) {
            #pragma unroll
            for (int kc = 0; kc < 8; ++kc) {
                const float* ep = e + (size_t)(kc * 32 + quad * 8) * KC
                                    + s * 512 + g * 64 + col0;
                #pragma unroll
                for (int nt = 0; nt < 4; ++nt) {
                    const float* epn = ep + nt * 16;
                    float bvv[8];
                    #pragma unroll
                    for (int j = 0; j < 8; ++j)
                        bvv[j] = epn[(size_t)j * KC];
                    int4v hw, lw;
                    #pragma unroll
                    for (int p = 0; p < 4; ++p) {
                        unsigned u0 = __float_as_uint(bvv[2 * p]);
                        unsigned u1 = __float_as_uint(bvv[2 * p + 1]);
                        hw[p] = (int)__builtin_amdgcn_perm(u1, u0, 0x07060302u);
                        float l0 = bvv[2 * p]     - __uint_as_float(u0 & 0xffff0000u);
                        float l1 = bvv[2 * p + 1] - __uint_as_float(u1 & 0xffff0000u);
                        lw[p] = (int)__builtin_amdgcn_perm(__float_as_uint(l1),
                                                           __float_as_uint(l0),
                                                           0x07060302u);
                    }
                    bf16x8 bh = __builtin_bit_cast(bf16x8, hw);
                    bf16x8 bl = __builtin_bit_cast(bf16x8, lw);
                    acc[nt] = __builtin_amdgcn_mfma_f32_16x16x32_bf16(ah[kc], bh, acc[nt], 0, 0, 0);
                    acc[nt] = __builtin_amdgcn_mfma_f32_16x16x32_bf16(ah[kc], bl, acc[nt], 0, 0, 0);
                    acc[nt] = __builtin_amdgcn_mfma_f32_16x16x32_bf16(al[kc], bh, acc[nt], 0, 0, 0);
                }
            }
            SCORE_MERGE(g);
        }
    }

    // ---- per-wave partial write: lanes col0==0 own 4 rows each
    if (col0 == 0) {
        #pragma unroll
        for (int r = 0; r < 4; ++r) {
            int rl = w * 16 + quad * 4 + r;
            out[PART_V + s * BN + row0 + rl] = bv[r];
            out[PART_I + s * BN + row0 + rl] = (float)(s * 512 + bi_[r]);
        }
    }
}

// ---------------------------------------------------------------- kernel 3m
// Merge slice partials -> final idx + counts.
__global__ __launch_bounds__(256) void k_merge(const int* __restrict__ mask,
                                               float* __restrict__ ws,
                                               float* __restrict__ out) {
    int row = blockIdx.x * 256 + threadIdx.x;
    float v0 = out[PART_V + row];
    float v1 = out[PART_V + BN + row];
    int i0 = (int)out[PART_I + row];
    int i1 = (int)out[PART_I + BN + row];
    float bvv = v0; int bii = i0;
    if (v1 < bvv || (v1 == bvv && i1 < bii)) { bvv = v1; bii = i1; }
    int m = mask[row];
    out[IDX_OFF + row] = m ? (float)bii : -1.0f;
    if (m) atomicAdd(&ws[WS_COUNTS + bii], 1.0f);
}

// ---------------------------------------------------------------- kernel 3b
// Streaming epilogue: recompute xb (fp32) from x, gather q from eT rows
// (coalesced), write quantized output + accumulate loss.
__global__ __launch_bounds__(256) void k_epi(
        const float* __restrict__ x, const int* __restrict__ mask,
        const float* __restrict__ e, const float* __restrict__ gamma,
        const float* __restrict__ beta,
        const float* __restrict__ ws, float* __restrict__ out,
        int use_et, int et_off) {
    __shared__ __align__(16) float muS[DIM], scS[DIM], btS[DIM];
    __shared__ float wred[4];
    const int tid = threadIdx.x;
    const int row0 = blockIdx.x * 32;
    const int w = tid >> 6;
    const int lane = tid & 63;
    {
        float cnt = ws[WS_COUNT];
        float nv = fmaxf(cnt, 1.f);
        float mu = ws[WS_SUM + tid] / nv;
        float var = ws[WS_SUMSQ + tid] / nv - mu * mu;
        var = fmaxf(var, 0.f);
        muS[tid] = mu;
        scS[tid] = rsqrtf(var + BN_EPS) * gamma[tid];
        btS[tid] = beta[tid];
    }
    __syncthreads();

    const int d0 = lane * 4;
    fvec4 mu4 = *(const fvec4*)&muS[d0];
    fvec4 sc4 = *(const fvec4*)&scS[d0];
    fvec4 bt4 = *(const fvec4*)&btS[d0];
    const float* et = ws + et_off;
    float lacc = 0.f;
    #pragma unroll
    for (int rr = 0; rr < 8; ++rr) {
        const int row = row0 + w * 8 + rr;
        const int m = mask[row];
        const float fm = (float)m;
        const int idx = m ? (int)out[IDX_OFF + row] : 0;
        fvec4 xv = nt_ld4(&x[(size_t)row * DIM + d0]);
        fvec4 g;
        if (use_et) {
            g = nt_ld4(&et[(size_t)idx * DIM + d0]);
        } else {
            g.x = e[(size_t)(d0 + 0) * KC + idx];
            g.y = e[(size_t)(d0 + 1) * KC + idx];
            g.z = e[(size_t)(d0 + 2) * KC + idx];
            g.w = e[(size_t)(d0 + 3) * KC + idx];
        }
        fvec4 q;
        float dsum = 0.f;
        #pragma unroll
        for (int i = 0; i < 4; ++i) {
            float xb = fmaf(xv[i] - mu4[i], sc4[i], bt4[i]);
            float diff = xb - g[i];
            dsum = fmaf(diff, diff, dsum);
            q[i] = fm * g[i];
        }
        lacc = fmaf(fm, dsum, lacc);
        __builtin_nontemporal_store(q, (fvec4*)&out[(size_t)row * DIM + d0]);
    }
    #pragma unroll
    for (int off2 = 32; off2 > 0; off2 >>= 1)
        lacc += __shfl_down(lacc, off2, 64);
    if (lane == 0) wred[w] = lacc;
    __syncthreads();
    if (tid == 0)
        atomicAdd((float*)&ws[WS_LOSS], wred[0] + wred[1] + wred[2] + wred[3]);
}

// ---------------------------------------------------------------- kernel 4
__global__ __launch_bounds__(256) void k_final(const float* __restrict__ ws,
                                               float* __restrict__ out) {
    int t = threadIdx.x;
    __shared__ float wr[4];
    float nv = fmaxf(ws[WS_COUNT], 1.f);
    float acc = 0.f;
    for (int j = t; j < KC; j += 256) {
        float p = ws[WS_COUNTS + j] / nv;
        acc = fmaf(p, logf(p + 1e-10f), acc);
    }
    #pragma unroll
    for (int off = 32; off > 0; off >>= 1) acc += __shfl_down(acc, off, 64);
    if ((t & 63) == 0) wr[t >> 6] = acc;
    __syncthreads();
    if (t == 0) {
        float ent = wr[0] + wr[1] + wr[2] + wr[3];
        float loss = ws[WS_LOSS] / (nv * (float)DIM);
        out[LOSS0_OFF] = loss;
        out[LOSS1_OFF] = loss;
        out[PERP_OFF] = expf(-ent);
    }
}

// ---------------------------------------------------------------- launch
extern "C" void kernel_launch(void* const* d_in, const int* in_sizes, int n_in,
                              void* d_out, int out_size, void* d_ws, size_t ws_size,
                              hipStream_t stream) {
    const float* x     = (const float*)d_in[0];
    const int*   amask = (const int*)d_in[1];
    const float* e     = (const float*)d_in[2];
    const float* gamma = (const float*)d_in[3];
    const float* beta  = (const float*)d_in[4];
    float* out = (float*)d_out;
    float* ws  = (float*)d_ws;

    size_t need_pk = (size_t)(WS_ETX + KC * DIM) * sizeof(float);    // ~2.03 MB
    size_t need_et = (size_t)(WS_ET_LEG + KC * DIM) * sizeof(float); // ~1.03 MB
    int use_pk = ws_size >= need_pk;
    int use_et = use_pk ? 1 : (ws_size >= need_et ? 1 : 0);
    int et_off = use_pk ? WS_ETX : WS_ET_LEG;

    (void)hipMemsetAsync(d_ws, 0, 8192, stream);

    k_pre<<<324, 256, 0, stream>>>(x, amask, e, ws, use_et, use_pk, et_off);
    k_main_mfma<<<512, 512, 0, stream>>>(x, amask, e, gamma, beta, ws, out,
                                         use_pk);
    k_merge<<<BN / 256, 256, 0, stream>>>(amask, ws, out);
    k_epi<<<BN / 32, 256, 0, stream>>>(x, amask, e, gamma, beta, ws, out,
                                       use_et, et_off);
    k_final<<<1, 256, 0, stream>>>(ws, out);
}

// Round 7
// 292.476 us; speedup vs baseline: 1.1098x; 1.0726x over previous
//
#include <hip/hip_runtime.h>
#include <math.h>

// Problem constants
#define BN   32768
#define DIM  256
#define KC   1024
#define BN_EPS 1e-5f

// Output layout (floats) in d_out
#define QX_SIZE   (BN * DIM)
#define LOSS0_OFF (QX_SIZE)
#define LOSS1_OFF (QX_SIZE + 1)
#define IDX_OFF   (QX_SIZE + 2)
#define PERP_OFF  (QX_SIZE + 2 + BN)

// Fallback scratch partials in the (later overwritten) QX region of out:
#define PART_V 0           // [4][BN] slice-min values
#define PART_I (4 * BN)    // [4][BN] slice-argmin indices (as float)

// Workspace (float offsets)
#define WS_SUM    0     // 256
#define WS_SUMSQ  256   // 256
#define WS_COUNT  512   // 1
#define WS_LOSS   513   // 1
#define WS_COUNTS 1024  // 1024
#define WS_CNORM  3072  // 1024
#define WS_PK     8192                  // packed B chunks, 262144 floats (1MB)
#define WS_ETX    (8192 + 262144)       // eT [K][D] f32 (packed layout)
#define WS_MINKEY (8192 + 262144 + 262144) // [BN] u64 argmin keys (2*BN floats)
#define WS_ET_LEG 8192                  // eT offset in legacy (small-ws) layout

#define NSLICE 4
#define SLICEK (KC / NSLICE)            // 256 codes per slice

typedef short bf16x8  __attribute__((ext_vector_type(8)));
typedef float f32x4   __attribute__((ext_vector_type(4)));
typedef float fvec4   __attribute__((ext_vector_type(4)));
typedef int   int4v   __attribute__((ext_vector_type(4)));
typedef unsigned long long u64;

static __device__ inline unsigned short f2bf(float f) {
    unsigned int u = __float_as_uint(f);
    return (unsigned short)((u + 0x7FFFu + ((u >> 16) & 1u)) >> 16);
}
static __device__ inline fvec4 nt_ld4(const void* p) {
    return __builtin_nontemporal_load((const fvec4*)p);
}
static __device__ inline void nt_st(float* p, float v) {
    __builtin_nontemporal_store(v, p);
}
// order-preserving float -> u32 (for atomicMin argmin keys)
static __device__ inline unsigned enc_f32(float f) {
    unsigned u = __float_as_uint(f);
    return (u & 0x80000000u) ? ~u : (u | 0x80000000u);
}

// ---------------------------------------------------------------- kernel 1
// Blocks 0..255: masked stats. 256..259: cnorm. 260..323: transpose + pack.
__global__ __launch_bounds__(256) void k_pre(const float* __restrict__ x,
                                             const int* __restrict__ mask,
                                             const float* __restrict__ e,
                                             float* __restrict__ ws,
                                             int use_et, int use_pk, int et_off) {
    int t = threadIdx.x;
    int b = blockIdx.x;
    if (b >= 260) {                        // transpose tiles 64d x 64k
        if (!use_et) return;
        int b2 = b - 260;
        int d0 = (b2 >> 4) * 64;           // contraction (feature) rows
        int k0 = (b2 & 15) * 64;           // codes
        __shared__ float tile[64][65];
        int c = t & 63;
        int rq = t >> 6;
        #pragma unroll
        for (int p = 0; p < 16; ++p) {
            int dd = p * 4 + rq;
            tile[dd][c] = e[(size_t)(d0 + dd) * KC + k0 + c];
        }
        __syncthreads();
        #pragma unroll
        for (int p = 0; p < 16; ++p) {
            int kk = p * 4 + rq;
            nt_st(&ws[et_off + (size_t)(k0 + kk) * DIM + d0 + c], tile[c][kk]);
        }
        if (use_pk) {
            // Pack chunk-ordered B: chunk (G=code-group,kcg=k-chunk) is 8KB:
            // frag (nt,h) 1KB, lane (quad=k-sub, col0=code) 16B.
            // Truncate split bit-identical to earlier rounds.
            char* pk = (char*)(ws + WS_PK);
            int lane2 = t & 63;
            int fgrp = t >> 6;              // 0..3
            int quad2 = lane2 >> 4, col2 = lane2 & 15;
            int G = b2 & 15;
            #pragma unroll
            for (int p = 0; p < 4; ++p) {
                int fi = fgrp * 4 + p;      // 0..15
                int kcl = fi >> 3;          // 0..1
                int nt = (fi >> 1) & 3;
                int h = fi & 1;
                int kcg = (b2 >> 4) * 2 + kcl;
                bf16x8 ov;
                #pragma unroll
                for (int j = 0; j < 8; ++j) {
                    float v = tile[kcl * 32 + quad2 * 8 + j][nt * 16 + col2];
                    unsigned u = __float_as_uint(v);
                    if (h == 0) {
                        ov[j] = (short)(u >> 16);
                    } else {
                        float lf = v - __uint_as_float(u & 0xffff0000u);
                        ov[j] = (short)(__float_as_uint(lf) >> 16);
                    }
                }
                size_t off = ((size_t)((G * 8 + kcg) * 8 + nt * 2 + h) << 10)
                             + (size_t)lane2 * 16;
                *(bf16x8*)(pk + off) = ov;
            }
        }
        return;
    }
    if (b >= 256) {                        // cnorm
        int k = (b - 256) * 256 + t;
        float acc = 0.f;
        #pragma unroll 8
        for (int d = 0; d < DIM; ++d) {
            float v = e[(size_t)d * KC + k];
            acc = fmaf(v, v, acc);
        }
        ws[WS_CNORM + k] = acc;
        return;
    }
    __shared__ float s4[4 * 256];
    __shared__ float q4[4 * 256];
    __shared__ float cntS[4];
    int c4 = t & 63;
    int rsub = t >> 6;
    float s0=0.f,s1=0.f,s2=0.f,s3=0.f, q0=0.f,q1=0.f,q2=0.f,q3=0.f, cnt=0.f;
    int rbase = b * 4 + rsub;
    for (int i = 0; i < 32; ++i) {
        int r = rbase + i * 1024;
        float m = (float)mask[r];
        fvec4 v = nt_ld4(&x[(size_t)r * DIM + c4 * 4]);
        cnt += m;
        float m0 = m*v.x, m1 = m*v.y, m2 = m*v.z, m3 = m*v.w;
        s0 += m0; s1 += m1; s2 += m2; s3 += m3;
        q0 = fmaf(m0, v.x, q0); q1 = fmaf(m1, v.y, q1);
        q2 = fmaf(m2, v.z, q2); q3 = fmaf(m3, v.w, q3);
    }
    int f = c4 * 4;
    s4[rsub * 256 + f + 0] = s0; s4[rsub * 256 + f + 1] = s1;
    s4[rsub * 256 + f + 2] = s2; s4[rsub * 256 + f + 3] = s3;
    q4[rsub * 256 + f + 0] = q0; q4[rsub * 256 + f + 1] = q1;
    q4[rsub * 256 + f + 2] = q2; q4[rsub * 256 + f + 3] = q3;
    if (c4 == 0) cntS[rsub] = cnt;
    __syncthreads();
    float stot = s4[t] + s4[256 + t] + s4[512 + t] + s4[768 + t];
    float qtot = q4[t] + q4[256 + t] + q4[512 + t] + q4[768 + t];
    atomicAdd(&ws[WS_SUM + t], stot);
    atomicAdd(&ws[WS_SUMSQ + t], qtot);
    if (t == 0)
        atomicAdd(&ws[WS_COUNT], cntS[0] + cntS[1] + cntS[2] + cntS[3]);
}

// ---------------------------------------------------------------- kernel 3
// MFMA main, 4-way codebook-sliced. 512 threads (8 waves), 128 rows/block,
// slice = 256 codes -> per-block B = 256 KB. Grid 1024 = 256 rb x 4 slices.
// Chunk = 64 codes x 32 k (8KB), 4-slot LDS ring, depth-2, vmcnt(2).
// Cross-slice merge: one atomicMin(u64 key) per row per block into ws.

#define CHUNK_COMPUTE(slot, kcc)                                             \
    {                                                                        \
        const char* bufb = &Bs[(slot) * 8192];                               \
        __builtin_amdgcn_s_setprio(1);                                       \
        _Pragma("unroll")                                                    \
        for (int nt = 0; nt < 4; ++nt) {                                     \
            bf16x8 bh = *(const bf16x8*)(bufb + (nt * 2 + 0) * 1024 + lane * 16); \
            bf16x8 bl = *(const bf16x8*)(bufb + (nt * 2 + 1) * 1024 + lane * 16); \
            acc[nt] = __builtin_amdgcn_mfma_f32_16x16x32_bf16(ah[kcc], bh, acc[nt], 0, 0, 0); \
            acc[nt] = __builtin_amdgcn_mfma_f32_16x16x32_bf16(ah[kcc], bl, acc[nt], 0, 0, 0); \
            acc[nt] = __builtin_amdgcn_mfma_f32_16x16x32_bf16(al[kcc], bh, acc[nt], 0, 0, 0); \
        }                                                                    \
        __builtin_amdgcn_s_setprio(0);                                       \
    }

#define SCORE_MERGE(gg)                                                      \
    {                                                                        \
        _Pragma("unroll")                                                    \
        for (int r = 0; r < 4; ++r) {                                        \
            float v = 3.4e38f; int ii = 0;                                   \
            _Pragma("unroll")                                                \
            for (int nt = 0; nt < 4; ++nt) {                                 \
                int kl = (gg) * 64 + nt * 16 + col0;                         \
                float sc = fmaf(-2.f, acc[nt][r], cnS[kl]);                  \
                if (sc < v) { v = sc; ii = kl; }                             \
            }                                                                \
            _Pragma("unroll")                                                \
            for (int m2 = 1; m2 < 16; m2 <<= 1) {                            \
                float v2 = __shfl_xor(v, m2, 64);                            \
                int   i2 = __shfl_xor(ii, m2, 64);                           \
                if (v2 < v || (v2 == v && i2 < ii)) { v = v2; ii = i2; }     \
            }                                                                \
            if (v < bv[r] || (v == bv[r] && ii < bi_[r])) {                  \
                bv[r] = v; bi_[r] = ii;                                      \
            }                                                                \
        }                                                                    \
        _Pragma("unroll")                                                    \
        for (int nt = 0; nt < 4; ++nt)                                       \
            acc[nt] = (f32x4){0.f, 0.f, 0.f, 0.f};                           \
    }

__global__ __launch_bounds__(512, 4) void k_main_mfma(
        const float* __restrict__ x, const int* __restrict__ mask,
        const float* __restrict__ e, const float* __restrict__ gamma,
        const float* __restrict__ beta,
        const float* __restrict__ ws, float* __restrict__ out,
        int use_pk, int use_mk) {
    __shared__ __align__(16) char Bs[4 * 8192];   // 32 KB B ring
    __shared__ float muS[DIM], scS[DIM], btS[DIM];
    __shared__ float cnS[SLICEK];

    const int tid = threadIdx.x;
    const int rb = blockIdx.x >> 2;
    const int s = blockIdx.x & 3;        // codebook slice
    const int row0 = rb * 128;
    const int w = tid >> 6;              // 0..7
    const int lane = tid & 63;
    const int quad = lane >> 4;
    const int col0 = lane & 15;

    if (tid < 256) {
        float cnt = ws[WS_COUNT];
        float nv = fmaxf(cnt, 1.f);
        float mu = ws[WS_SUM + tid] / nv;
        float var = ws[WS_SUMSQ + tid] / nv - mu * mu;
        var = fmaxf(var, 0.f);
        muS[tid] = mu;
        scS[tid] = rsqrtf(var + BN_EPS) * gamma[tid];
        btS[tid] = beta[tid];
    }
    if (tid < SLICEK)
        cnS[tid] = ws[WS_CNORM + s * SLICEK + tid];
    __syncthreads();

    // ---- A fragments in registers: wave w rows row0+w*16+col0
    bf16x8 ah[8], al[8];
    {
        const float* xr = x + (size_t)(row0 + w * 16 + col0) * DIM;
        #pragma unroll
        for (int kc = 0; kc < 8; ++kc) {
            int k0 = kc * 32 + quad * 8;
            fvec4 v0 = nt_ld4(xr + k0);
            fvec4 v1 = nt_ld4(xr + k0 + 4);
            float xv[8] = {v0.x, v0.y, v0.z, v0.w, v1.x, v1.y, v1.z, v1.w};
            bf16x8 hv, lv;
            #pragma unroll
            for (int j = 0; j < 8; ++j) {
                float xb = fmaf(xv[j] - muS[k0 + j], scS[k0 + j], btS[k0 + j]);
                unsigned short h = f2bf(xb);
                float hf = __uint_as_float((unsigned)h << 16);
                hv[j] = (short)h;
                lv[j] = (short)f2bf(xb - hf);
            }
            ah[kc] = hv;
            al[kc] = lv;
        }
    }
    // retire A loads so the counted-vmcnt math sees only stage loads
    asm volatile("s_waitcnt vmcnt(0)" ::: "memory");
    __builtin_amdgcn_sched_barrier(0);

    f32x4 acc[4];
    #pragma unroll
    for (int nt = 0; nt < 4; ++nt)
        acc[nt] = (f32x4){0.f, 0.f, 0.f, 0.f};
    float bv[4] = {3.4e38f, 3.4e38f, 3.4e38f, 3.4e38f};
    int   bi_[4] = {0, 0, 0, 0};

    if (use_pk) {
        const char* pkb = (const char*)(ws + WS_PK) + (size_t)s * 262144;
        auto stage = [&](int c2, int slot) {
            const char* src = pkb + (size_t)c2 * 8192 + w * 1024 + lane * 16;
            char* dst = &Bs[slot * 8192 + w * 1024];
            __builtin_amdgcn_global_load_lds(
                (const __attribute__((address_space(1))) void*)src,
                (__attribute__((address_space(3))) void*)dst, 16, 0, 0);
        };
        stage(0, 0);
        stage(1, 1);
        for (int g = 0; g < 3; ++g) {
            #pragma unroll
            for (int kc = 0; kc < 8; ++kc) {
                stage(g * 8 + kc + 2, (kc + 2) & 3);
                asm volatile("s_waitcnt vmcnt(2)" ::: "memory");
                __builtin_amdgcn_s_barrier();
                __builtin_amdgcn_sched_barrier(0);
                CHUNK_COMPUTE(kc & 3, kc);
            }
            SCORE_MERGE(g);
        }
        {   // g = 3, counted drain
            #pragma unroll
            for (int kc = 0; kc < 8; ++kc) {
                if (kc < 6) {
                    stage(24 + kc + 2, (kc + 2) & 3);
                    asm volatile("s_waitcnt vmcnt(2)" ::: "memory");
                } else if (kc == 6) {
                    asm volatile("s_waitcnt vmcnt(1)" ::: "memory");
                } else {
                    asm volatile("s_waitcnt vmcnt(0)" ::: "memory");
                }
                __builtin_amdgcn_s_barrier();
                __builtin_amdgcn_sched_barrier(0);
                CHUNK_COMPUTE(kc & 3, kc);
            }
            SCORE_MERGE(3);
        }
    } else {
        // fallback: scattered loads from e (slice-local), in-reg split
        for (int g = 0; g < 4; ++g) {
            #pragma unroll
            for (int kc = 0; kc < 8; ++kc) {
                const float* ep = e + (size_t)(kc * 32 + quad * 8) * KC
                                    + s * SLICEK + g * 64 + col0;
                #pragma unroll
                for (int nt = 0; nt < 4; ++nt) {
                    const float* epn = ep + nt * 16;
                    float bvv[8];
                    #pragma unroll
                    for (int j = 0; j < 8; ++j)
                        bvv[j] = epn[(size_t)j * KC];
                    int4v hw, lw;
                    #pragma unroll
                    for (int p = 0; p < 4; ++p) {
                        unsigned u0 = __float_as_uint(bvv[2 * p]);
                        unsigned u1 = __float_as_uint(bvv[2 * p + 1]);
                        hw[p] = (int)__builtin_amdgcn_perm(u1, u0, 0x07060302u);
                        float l0 = bvv[2 * p]     - __uint_as_float(u0 & 0xffff0000u);
                        float l1 = bvv[2 * p + 1] - __uint_as_float(u1 & 0xffff0000u);
                        lw[p] = (int)__builtin_amdgcn_perm(__float_as_uint(l1),
                                                           __float_as_uint(l0),
                                                           0x07060302u);
                    }
                    bf16x8 bh = __builtin_bit_cast(bf16x8, hw);
                    bf16x8 bl = __builtin_bit_cast(bf16x8, lw);
                    acc[nt] = __builtin_amdgcn_mfma_f32_16x16x32_bf16(ah[kc], bh, acc[nt], 0, 0, 0);
                    acc[nt] = __builtin_amdgcn_mfma_f32_16x16x32_bf16(ah[kc], bl, acc[nt], 0, 0, 0);
                    acc[nt] = __builtin_amdgcn_mfma_f32_16x16x32_bf16(al[kc], bh, acc[nt], 0, 0, 0);
                }
            }
            SCORE_MERGE(g);
        }
    }

    // ---- per-wave result: lanes col0==0 own 4 rows each
    if (col0 == 0) {
        if (use_mk) {
            u64* mk = (u64*)(ws + WS_MINKEY);
            #pragma unroll
            for (int r = 0; r < 4; ++r) {
                int rl = w * 16 + quad * 4 + r;
                u64 key = ((u64)enc_f32(bv[r]) << 32)
                          | (unsigned)(s * SLICEK + bi_[r]);
                atomicMin(&mk[row0 + rl], key);
            }
        } else {
            #pragma unroll
            for (int r = 0; r < 4; ++r) {
                int rl = w * 16 + quad * 4 + r;
                out[PART_V + s * BN + row0 + rl] = bv[r];
                out[PART_I + s * BN + row0 + rl] = (float)(s * SLICEK + bi_[r]);
            }
        }
    }
}

// ---------------------------------------------------------------- kernel 3m
// Fallback only: merge 4 slice partials -> final idx + counts.
__global__ __launch_bounds__(256) void k_merge(const int* __restrict__ mask,
                                               float* __restrict__ ws,
                                               float* __restrict__ out) {
    int row = blockIdx.x * 256 + threadIdx.x;
    float bvv = out[PART_V + row];
    int bii = (int)out[PART_I + row];
    #pragma unroll
    for (int s = 1; s < NSLICE; ++s) {
        float v = out[PART_V + s * BN + row];
        int i = (int)out[PART_I + s * BN + row];
        if (v < bvv || (v == bvv && i < bii)) { bvv = v; bii = i; }
    }
    int m = mask[row];
    out[IDX_OFF + row] = m ? (float)bii : -1.0f;
    if (m) atomicAdd(&ws[WS_COUNTS + bii], 1.0f);
}

// ---------------------------------------------------------------- kernel 3b
// Streaming epilogue: decode argmin keys (use_mk), write idx + counts,
// recompute xb (fp32) from x, gather q from eT rows, write quantized
// output + accumulate loss.
__global__ __launch_bounds__(256) void k_epi(
        const float* __restrict__ x, const int* __restrict__ mask,
        const float* __restrict__ e, const float* __restrict__ gamma,
        const float* __restrict__ beta,
        const float* __restrict__ ws, float* __restrict__ out,
        int use_et, int et_off, int use_mk) {
    __shared__ __align__(16) float muS[DIM], scS[DIM], btS[DIM];
    __shared__ float wred[4];
    const int tid = threadIdx.x;
    const int row0 = blockIdx.x * 32;
    const int w = tid >> 6;
    const int lane = tid & 63;
    {
        float cnt = ws[WS_COUNT];
        float nv = fmaxf(cnt, 1.f);
        float mu = ws[WS_SUM + tid] / nv;
        float var = ws[WS_SUMSQ + tid] / nv - mu * mu;
        var = fmaxf(var, 0.f);
        muS[tid] = mu;
        scS[tid] = rsqrtf(var + BN_EPS) * gamma[tid];
        btS[tid] = beta[tid];
    }
    __syncthreads();

    // decode this wave's 8 row keys (coalesced u64 reads, lanes 0..7)
    u64 mykey = 0;
    if (use_mk) {
        const u64* mk = (const u64*)(ws + WS_MINKEY);
        if (lane < 8) mykey = mk[row0 + w * 8 + lane];
    }

    const int d0 = lane * 4;
    fvec4 mu4 = *(const fvec4*)&muS[d0];
    fvec4 sc4 = *(const fvec4*)&scS[d0];
    fvec4 bt4 = *(const fvec4*)&btS[d0];
    const float* et = ws + et_off;
    float lacc = 0.f;
    #pragma unroll
    for (int rr = 0; rr < 8; ++rr) {
        const int row = row0 + w * 8 + rr;
        const int m = mask[row];
        const float fm = (float)m;
        int idx;
        if (use_mk) {
            u64 k = __shfl(mykey, rr, 64);
            idx = (int)(unsigned)(k & 0xFFFFFFFFull);
            if (lane == 0) {
                out[IDX_OFF + row] = m ? (float)idx : -1.0f;
                if (m) atomicAdd((float*)&ws[WS_COUNTS + idx], 1.0f);
            }
            if (!m) idx = 0;
        } else {
            idx = m ? (int)out[IDX_OFF + row] : 0;
        }
        fvec4 xv = nt_ld4(&x[(size_t)row * DIM + d0]);
        fvec4 g;
        if (use_et) {
            g = nt_ld4(&et[(size_t)idx * DIM + d0]);
        } else {
            g.x = e[(size_t)(d0 + 0) * KC + idx];
            g.y = e[(size_t)(d0 + 1) * KC + idx];
            g.z = e[(size_t)(d0 + 2) * KC + idx];
            g.w = e[(size_t)(d0 + 3) * KC + idx];
        }
        fvec4 q;
        float dsum = 0.f;
        #pragma unroll
        for (int i = 0; i < 4; ++i) {
            float xb = fmaf(xv[i] - mu4[i], sc4[i], bt4[i]);
            float diff = xb - g[i];
            dsum = fmaf(diff, diff, dsum);
            q[i] = fm * g[i];
        }
        lacc = fmaf(fm, dsum, lacc);
        __builtin_nontemporal_store(q, (fvec4*)&out[(size_t)row * DIM + d0]);
    }
    #pragma unroll
    for (int off2 = 32; off2 > 0; off2 >>= 1)
        lacc += __shfl_down(lacc, off2, 64);
    if (lane == 0) wred[w] = lacc;
    __syncthreads();
    if (tid == 0)
        atomicAdd((float*)&ws[WS_LOSS], wred[0] + wred[1] + wred[2] + wred[3]);
}

// ---------------------------------------------------------------- kernel 4
__global__ __launch_bounds__(256) void k_final(const float* __restrict__ ws,
                                               float* __restrict__ out) {
    int t = threadIdx.x;
    __shared__ float wr[4];
    float nv = fmaxf(ws[WS_COUNT], 1.f);
    float acc = 0.f;
    for (int j = t; j < KC; j += 256) {
        float p = ws[WS_COUNTS + j] / nv;
        acc = fmaf(p, logf(p + 1e-10f), acc);
    }
    #pragma unroll
    for (int off = 32; off > 0; off >>= 1) acc += __shfl_down(acc, off, 64);
    if ((t & 63) == 0) wr[t >> 6] = acc;
    __syncthreads();
    if (t == 0) {
        float ent = wr[0] + wr[1] + wr[2] + wr[3];
        float loss = ws[WS_LOSS] / (nv * (float)DIM);
        out[LOSS0_OFF] = loss;
        out[LOSS1_OFF] = loss;
        out[PERP_OFF] = expf(-ent);
    }
}

// ---------------------------------------------------------------- launch
extern "C" void kernel_launch(void* const* d_in, const int* in_sizes, int n_in,
                              void* d_out, int out_size, void* d_ws, size_t ws_size,
                              hipStream_t stream) {
    const float* x     = (const float*)d_in[0];
    const int*   amask = (const int*)d_in[1];
    const float* e     = (const float*)d_in[2];
    const float* gamma = (const float*)d_in[3];
    const float* beta  = (const float*)d_in[4];
    float* out = (float*)d_out;
    float* ws  = (float*)d_ws;

    size_t need_mk = (size_t)(WS_MINKEY + 2 * BN) * sizeof(float);   // ~2.39 MB
    size_t need_pk = (size_t)(WS_ETX + KC * DIM) * sizeof(float);    // ~2.03 MB
    size_t need_et = (size_t)(WS_ET_LEG + KC * DIM) * sizeof(float); // ~1.03 MB
    int use_pk = ws_size >= need_pk;
    int use_mk = use_pk && (ws_size >= need_mk);
    int use_et = use_pk ? 1 : (ws_size >= need_et ? 1 : 0);
    int et_off = use_pk ? WS_ETX : WS_ET_LEG;

    (void)hipMemsetAsync(d_ws, 0, 8192, stream);
    if (use_mk)
        (void)hipMemsetAsync((char*)d_ws + (size_t)WS_MINKEY * 4, 0xFF,
                             (size_t)BN * 8, stream);

    k_pre<<<324, 256, 0, stream>>>(x, amask, e, ws, use_et, use_pk, et_off);
    k_main_mfma<<<256 * NSLICE, 512, 0, stream>>>(x, amask, e, gamma, beta, ws,
                                                  out, use_pk, use_mk);
    if (!use_mk)
        k_merge<<<BN / 256, 256, 0, stream>>>(amask, ws, out);
    k_epi<<<BN / 32, 256, 0, stream>>>(x, amask, e, gamma, beta, ws, out,
                                       use_et, et_off, use_mk);
    k_final<<<1, 256, 0, stream>>>(ws, out);
}